// Round 12
// baseline (272.078 us; speedup 1.0000x reference)
//
#include <hip/hip_runtime.h>

// VQ nearest-embedding, fused split-fp16 MFMA, double-buffered LDS.
// argmin_k ||x-e_k||^2 == argmin_k (0.5*||e_k||^2 - x.e_k).
// x = xh+xl, e = eh+el (fp16 RNE splits); 3 MFMA terms (hh, hl, lh).
// R15 (138us): conflicts 6.3M->0 (staging remap). R16 (139us): nodrain
//      barrier neutral => loads already complete at barriers (L2/L3 fast).
//      Remaining wall: LDS data pipe = 59% of chunk; reads 2304 cyc set
//      by geometry (16 waves x 32x64 tile => 4x read amplification).
// R17: 8 waves x 64x64 tile (acc[2][2], R5's verified MFMA block + C/D
//      map): 128 instead of 192 wave-b128 reads/chunk (-33% on the
//      dominant pipe). R11's version of this failed from its OWN layout
//      (LDB=32: reads 4-way conflicted) -- kept here: LDA=40 (reads
//      measured-free), bank-uniform staging maps (A: 16rows x 4quads
//      b128; B: 64-consecutive-code b128), distance-2 prefetch, nodrain
//      barriers. Split bits + per-acc hh/hl/lh order identical -> absmax 0.

typedef __attribute__((ext_vector_type(8))) _Float16 half8v;  // 8 fp16 = 4 VGPRs
typedef __attribute__((ext_vector_type(16))) float floatx16;  // 32x32 acc
typedef unsigned int uint;
typedef unsigned short ushort;

#define DD 256
#define KK 2048
#define SS 1024
#define NN 32768
#define MT 128      // latents per block
#define NTT 256     // codes per kt tile (8 tiles cover K=2048)
#define CD 32       // chunk K-depth (halfs)
#define LDA 40      // LDS row stride in fp16 elems (80 B: 16B-aligned)
#define MFMA_F16 __builtin_amdgcn_mfma_f32_32x32x16_f16

union HU { _Float16 f; ushort u; };

__device__ __forceinline__ void split16(float v, ushort& h, ushort& l) {
    HU a, b;
    a.f = (_Float16)v;                       // RNE
    b.f = (_Float16)(v - (float)a.f);
    h = a.u; l = b.u;
}

__device__ __forceinline__ uint pk(ushort a, ushort b) {
    return (uint)a | ((uint)b << 16);
}

// Raw barrier: drain LDS ops only; leave global loads (private VGPR
// destinations) in flight across the barrier.
__device__ __forceinline__ void barrier_nodrain() {
    asm volatile("s_waitcnt lgkmcnt(0)" ::: "memory");
    __builtin_amdgcn_s_barrier();
}

// 64 blocks: block b covers codes [b*32, b*32+32); 8 threads/code sum 32 d's.
__global__ __launch_bounds__(256) void hn_kernel(const float* __restrict__ emb,
                                                 float* __restrict__ hn) {
    __shared__ float red[256];
    const int tid = threadIdx.x;
    const int k = blockIdx.x * 32 + (tid & 31);
    const int j = tid >> 5;              // 0..7: d-chunk
    float a = 0.f;
#pragma unroll
    for (int i = 0; i < 32; ++i) {
        float e = emb[(size_t)(j * 32 + i) * KK + k];
        a += e * e;
    }
    red[tid] = a;
    __syncthreads();
    if (j == 0) {
        float s = a;
#pragma unroll
        for (int g = 1; g < 8; ++g) s += red[g * 32 + (tid & 31)];
        hn[k] = 0.5f * s;
    }
}

// emb (d,k) f32 -> epk quad-interleaved uint4 planes:
//   uint4 index (q*2 + p)*KK + k   holds, for plane p in {h,l}, code k,
//   packed d-pairs of quad q (element j = pack(d=8q+2j, d=8q+2j+1)).
__global__ __launch_bounds__(256) void pack_emb(const float* __restrict__ emb,
                                                uint4* __restrict__ epk) {
    int idx = blockIdx.x * 256 + threadIdx.x;     // 65536 = 32 quads * 2048 k
    int k = idx & (KK - 1);
    int q = idx >> 11;                            // d-quad: d = 8q..8q+7
    ushort h[8], l[8];
#pragma unroll
    for (int j = 0; j < 8; ++j) {
        float e = emb[(size_t)(8 * q + j) * KK + k];
        split16(e, h[j], l[j]);
    }
    uint4 H, L;
    H.x = pk(h[0], h[1]); H.y = pk(h[2], h[3]);
    H.z = pk(h[4], h[5]); H.w = pk(h[6], h[7]);
    L.x = pk(l[0], l[1]); L.y = pk(l[2], l[3]);
    L.z = pk(l[4], l[5]); L.w = pk(l[6], l[7]);
    epk[(size_t)(q * 2 + 0) * KK + k] = H;
    epk[(size_t)(q * 2 + 1) * KK + k] = L;
}

// PRE: B from quad-packed epk (dwordx4). !PRE: B from emb f32 + in-loop split.
template <bool PRE>
__global__ __launch_bounds__(512, 2) void vq_fused(
        const float* __restrict__ x, const float* __restrict__ emb,
        const float* __restrict__ hn, const uint4* __restrict__ epk,
        float* __restrict__ out) {
    __shared__ ushort Ah[2][MT * LDA], Al[2][MT * LDA];     // 10 KB each plane/buf
    __shared__ ushort Bh[2][NTT * LDA], Bl[2][NTT * LDA];   // 20 KB each plane/buf
    __shared__ float sv[4][MT];
    __shared__ int   sc[4][MT];
    __shared__ int   bc[MT];

    const int tid = threadIdx.x;
    const int lane = tid & 63;
    const int wid = tid >> 6;          // 8 waves: 2(m) x 4(n)
    const int colk = lane & 31;
    const int half = lane >> 5;
    const int wm = (wid & 1) * 64;     // wave covers m-tiles wm, wm+32
    const int wn = (wid >> 1) * 64;    // and n-tiles wn, wn+32

    const int base_n = blockIdx.x * MT;
    const int bq = base_n >> 10;          // batch (SS = 1024)
    const int sb = base_n & (SS - 1);     // spatial base

    // staging assignment (512 threads)
    // A: thread covers row lat_a, quad qa2 (halfs 8*qa2 .. 8*qa2+7).
    //    Wave = 16 rows x 4 quads: b128 writes hit every 16B-group 8x (free).
    const int lat_a = (tid & 15) + 16 * (tid >> 6);
    const int qa2 = (tid >> 4) & 3;
    // B: thread covers code cod_b, plane pB, all 4 quads of the chunk.
    const int cod_b = tid & 255;
    const int pB = tid >> 8;              // 0=h, 1=l

    // A global base: d = dt + 8*qa2 + j, latent sb + lat_a
    const float* xA = x + ((size_t)bq * DD + 8 * qa2) * SS + sb + lat_a;

    floatx16 acc[2][2];
#pragma unroll
    for (int i = 0; i < 2; ++i)
#pragma unroll
        for (int j = 0; j < 2; ++j) acc[i][j] = (floatx16)(0.0f);

    float bestv[2][16];
    int bestc[2][16];
#pragma unroll
    for (int t = 0; t < 2; ++t)
#pragma unroll
        for (int r = 0; r < 16; ++r) { bestv[t][r] = 3.4e38f; bestc[t][r] = 0; }

    // two named register sets (static indexing — no dynamic array idx)
    float fa0[8], fa1[8];
    uint4 ub0[4], ub1[4];       // PRE: 4 quads of this thread's plane
    float fb0[32], fb1[32];     // !PRE raw f32 (cold path)

    // ---- helpers ----
    auto issueA = [&](int c, float (&fa)[8]) {
        const int dt = (c & 7) * CD;
#pragma unroll
        for (int j = 0; j < 8; ++j) fa[j] = xA[(size_t)(dt + j) * SS];
    };
    auto issueB = [&](int c, uint4 (&ub)[4], float (&fb)[32]) {
        const int kt = c >> 3;
        const int dt = (c & 7) * CD;
        if constexpr (PRE) {
            const int qg = dt >> 3;
            const size_t kb = (size_t)kt * NTT + cod_b;
#pragma unroll
            for (int s = 0; s < 4; ++s)
                ub[s] = epk[(size_t)((qg + s) * 2 + pB) * KK + kb];
        } else {
#pragma unroll
            for (int i = 0; i < 32; ++i)
                fb[i] = emb[(size_t)(dt + i) * KK + (size_t)kt * NTT + cod_b];
        }
    };
    auto stageWrite = [&](int nxt, float (&fa)[8], uint4 (&ub)[4],
                          float (&fb)[32]) {
        ushort h[8], l[8];
#pragma unroll
        for (int j = 0; j < 8; ++j) split16(fa[j], h[j], l[j]);
        uint4 H, L;
        H.x = pk(h[0], h[1]); H.y = pk(h[2], h[3]);
        H.z = pk(h[4], h[5]); H.w = pk(h[6], h[7]);
        L.x = pk(l[0], l[1]); L.y = pk(l[2], l[3]);
        L.z = pk(l[4], l[5]); L.w = pk(l[6], l[7]);
        *reinterpret_cast<uint4*>(&Ah[nxt][lat_a * LDA + 8 * qa2]) = H;
        *reinterpret_cast<uint4*>(&Al[nxt][lat_a * LDA + 8 * qa2]) = L;
        ushort* Bp = pB ? &Bl[nxt][0] : &Bh[nxt][0];
        if constexpr (PRE) {
#pragma unroll
            for (int s = 0; s < 4; ++s)
                *reinterpret_cast<uint4*>(&Bp[cod_b * LDA + 8 * s]) = ub[s];
        } else {
            ushort hh[32], ll[32];
#pragma unroll
            for (int i = 0; i < 32; ++i) split16(fb[i], hh[i], ll[i]);
            const ushort* s_ = pB ? ll : hh;
#pragma unroll
            for (int s = 0; s < 4; ++s) {
                uint4 w;
                w.x = pk(s_[8 * s + 0], s_[8 * s + 1]);
                w.y = pk(s_[8 * s + 2], s_[8 * s + 3]);
                w.z = pk(s_[8 * s + 4], s_[8 * s + 5]);
                w.w = pk(s_[8 * s + 6], s_[8 * s + 7]);
                *reinterpret_cast<uint4*>(&Bp[cod_b * LDA + 8 * s]) = w;
            }
        }
    };
    auto compute = [&](int cur) {
        const int fo = colk * LDA + half * 8;
#pragma unroll
        for (int t = 0; t < 2; ++t) {
            const int o = t * 16;
            half8v ah0 = *reinterpret_cast<const half8v*>(&Ah[cur][fo + wm * LDA + o]);
            half8v ah1 = *reinterpret_cast<const half8v*>(&Ah[cur][fo + (wm + 32) * LDA + o]);
            half8v al0 = *reinterpret_cast<const half8v*>(&Al[cur][fo + wm * LDA + o]);
            half8v al1 = *reinterpret_cast<const half8v*>(&Al[cur][fo + (wm + 32) * LDA + o]);
            half8v bh0 = *reinterpret_cast<const half8v*>(&Bh[cur][fo + wn * LDA + o]);
            half8v bh1 = *reinterpret_cast<const half8v*>(&Bh[cur][fo + (wn + 32) * LDA + o]);
            half8v bl0 = *reinterpret_cast<const half8v*>(&Bl[cur][fo + wn * LDA + o]);
            half8v bl1 = *reinterpret_cast<const half8v*>(&Bl[cur][fo + (wn + 32) * LDA + o]);

            acc[0][0] = MFMA_F16(ah0, bh0, acc[0][0], 0, 0, 0);
            acc[0][0] = MFMA_F16(ah0, bl0, acc[0][0], 0, 0, 0);
            acc[0][0] = MFMA_F16(al0, bh0, acc[0][0], 0, 0, 0);

            acc[0][1] = MFMA_F16(ah0, bh1, acc[0][1], 0, 0, 0);
            acc[0][1] = MFMA_F16(ah0, bl1, acc[0][1], 0, 0, 0);
            acc[0][1] = MFMA_F16(al0, bh1, acc[0][1], 0, 0, 0);

            acc[1][0] = MFMA_F16(ah1, bh0, acc[1][0], 0, 0, 0);
            acc[1][0] = MFMA_F16(ah1, bl0, acc[1][0], 0, 0, 0);
            acc[1][0] = MFMA_F16(al1, bh0, acc[1][0], 0, 0, 0);

            acc[1][1] = MFMA_F16(ah1, bh1, acc[1][1], 0, 0, 0);
            acc[1][1] = MFMA_F16(ah1, bl1, acc[1][1], 0, 0, 0);
            acc[1][1] = MFMA_F16(al1, bh1, acc[1][1], 0, 0, 0);
        }
    };
    auto epilogue = [&](int kt) {
        const int cd0 = kt * NTT + wn + colk;
        const int cd1 = cd0 + 32;
        const float h0 = hn[cd0];
        const float h1 = hn[cd1];
#pragma unroll
        for (int tm = 0; tm < 2; ++tm) {
#pragma unroll
            for (int r = 0; r < 16; ++r) {
                float s0 = h0 - acc[tm][0][r];
                float s1 = h1 - acc[tm][1][r];
                float v = s0; int cd = cd0;
                if (s1 < s0) { v = s1; cd = cd1; }   // strict <: smaller code wins ties
                if (v < bestv[tm][r]) { bestv[tm][r] = v; bestc[tm][r] = cd; }
                acc[tm][0][r] = 0.f;
                acc[tm][1][r] = 0.f;
            }
        }
    };

    // ---- prologue: stage chunk 0, issue chunk 1 ----
    issueA(0, fa0); issueB(0, ub0, fb0);
    stageWrite(0, fa0, ub0, fb0);                // one exposed vmcnt wait
    issueA(1, fa1); issueB(1, ub1, fb1);         // stays in flight over barrier
    barrier_nodrain();

    // ---- main loop: 64 chunks (8 kt x 8 dt of K-depth 32), 2 per iter ----
    for (int cc = 0; cc < 32; ++cc) {
        const int c0 = cc * 2;
        // even step: cur=0, nxt=1; set0 free (data c0 already in LDS)
        if (c0 + 2 < 64) { issueA(c0 + 2, fa0); issueB(c0 + 2, ub0, fb0); }
        stageWrite(1, fa1, ub1, fb1);            // data(c0+1): issued 1 chunk ago
        compute(0);
        barrier_nodrain();

        // odd step: cur=1, nxt=0; set1 free
        const int c1 = c0 + 1;
        if (c1 + 2 < 64) { issueA(c1 + 2, fa1); issueB(c1 + 2, ub1, fb1); }
        if (c1 + 1 < 64) { stageWrite(0, fa0, ub0, fb0); }
        compute(1);
        if ((c1 & 7) == 7) epilogue(c1 >> 3);
        barrier_nodrain();
    }

    // ---- cross-lane argmin: butterfly over the 32 colk lanes ----
#pragma unroll
    for (int tm = 0; tm < 2; ++tm) {
#pragma unroll
        for (int r = 0; r < 16; ++r) {
            float v = bestv[tm][r];
            int cd = bestc[tm][r];
#pragma unroll
            for (int mk = 1; mk < 32; mk <<= 1) {
                float ov = __shfl_xor(v, mk);
                int oc = __shfl_xor(cd, mk);
                if (ov < v || (ov == v && oc < cd)) { v = ov; cd = oc; }
            }
            if (colk == 0) {
                const int row = (r & 3) + 8 * (r >> 2) + 4 * half;  // verified C/D map
                sv[wid >> 1][wm + tm * 32 + row] = v;
                sc[wid >> 1][wm + tm * 32 + row] = cd;
            }
        }
    }
    __syncthreads();
    // ---- combine the 4 n-wave groups ----
    if (tid < MT) {
        float v = sv[0][tid]; int cd = sc[0][tid];
#pragma unroll
        for (int g = 1; g < 4; ++g) {
            float ov = sv[g][tid]; int oc = sc[g][tid];
            if (ov < v || (ov == v && oc < cd)) { v = ov; cd = oc; }
        }
        bc[tid] = cd;
    }
    __syncthreads();
    // ---- fused gather: out[(bq*DD+d)*SS + sb + m] = emb[d*KK + bc[m]] ----
    {
        const int mq = tid & 31;     // float4 group along m (128 cols = 32 groups)
        const int dg = tid >> 5;     // 0..15, 16 d's each
        const int k0 = bc[mq * 4 + 0];
        const int k1 = bc[mq * 4 + 1];
        const int k2 = bc[mq * 4 + 2];
        const int k3 = bc[mq * 4 + 3];
#pragma unroll 4
        for (int dd = 0; dd < 16; ++dd) {
            const int d = dg * 16 + dd;
            const float* er = emb + (size_t)d * KK;
            float4 o = make_float4(er[k0], er[k1], er[k2], er[k3]);
            reinterpret_cast<float4*>(&out[((size_t)bq * DD + d) * SS + sb])[mq] = o;
        }
    }
}

extern "C" void kernel_launch(void* const* d_in, const int* in_sizes, int n_in,
                              void* d_out, int out_size, void* d_ws, size_t ws_size,
                              hipStream_t stream) {
    const float* x = (const float*)d_in[0];     // (32,256,32,32)
    const float* emb = (const float*)d_in[1];   // (256,2048)
    float* out = (float*)d_out;
    float* hn = (float*)d_ws;                   // 2048 f32 = 8 KB (proven safe)
    uint4* epk = (uint4*)((char*)d_ws + KK * sizeof(float));  // 2 MB packed emb

    // 32 quads * 2 planes * 2048 codes * 16 B = 2 MB
    const size_t need = (size_t)KK * 4 + (size_t)32 * 2 * KK * 16;

    hipLaunchKernelGGL(hn_kernel, dim3(KK / 32), dim3(256), 0, stream, emb, hn);
    if (ws_size >= need) {
        hipLaunchKernelGGL(pack_emb, dim3(65536 / 256), dim3(256), 0, stream,
                           emb, epk);
        hipLaunchKernelGGL((vq_fused<true>), dim3(NN / MT), dim3(512), 0, stream,
                           x, emb, hn, epk, out);
    } else {
        hipLaunchKernelGGL((vq_fused<false>), dim3(NN / MT), dim3(512), 0, stream,
                           x, emb, hn, epk, out);
    }
}